// Round 1
// baseline (502.606 us; speedup 1.0000x reference)
//
#include <hip/hip_runtime.h>

// Segmented argmax (first-max tie-break) via packed u64 atomicMax.
// packed = (pred_bits << 32) | (0xFFFFFFFF - edge_idx)
//  - pred is uniform [0,1) -> non-negative float, bit pattern is monotone
//  - larger packed  <=>  larger pred, then smaller edge index
//  - packed == 0 is unreachable (low word is 0 only for idx==0xFFFFFFFF),
//    so 0 == "no incoming edge" sentinel.

__global__ void edge_kernel(const float* __restrict__ pred,
                            const int* __restrict__ dst,
                            unsigned long long* __restrict__ best,
                            int e) {
    int i = blockIdx.x * blockDim.x + threadIdx.x;
    int stride = gridDim.x * blockDim.x;
    for (; i < e; i += stride) {
        float p = pred[i];
        int d = dst[i];
        unsigned long long packed =
            ((unsigned long long)__float_as_uint(p) << 32) |
            (unsigned long long)(0xFFFFFFFFu - (unsigned int)i);
        atomicMax(&best[d], packed);
    }
}

__global__ void node_kernel(const unsigned long long* __restrict__ best,
                            const int* __restrict__ matched,
                            const int* __restrict__ src,
                            float* __restrict__ out_matched,
                            float* __restrict__ out_winpred,
                            float* __restrict__ found,
                            int n) {
    int i = blockIdx.x * blockDim.x + threadIdx.x;
    if (i >= n) return;
    unsigned long long b = best[i];
    int m = matched[i];
    int nm = m;
    float wp = 0.0f;
    if (b != 0ULL) {
        wp = __uint_as_float((unsigned int)(b >> 32));
        unsigned int idx = 0xFFFFFFFFu - (unsigned int)(b & 0xFFFFFFFFu);
        if (m == -1 && wp > 0.5f) {
            nm = matched[src[idx]];
            *found = 1.0f;   // benign race: every writer stores 1.0f
        }
    }
    out_matched[i] = (float)nm;
    out_winpred[i] = wp;
}

extern "C" void kernel_launch(void* const* d_in, const int* in_sizes, int n_in,
                              void* d_out, int out_size, void* d_ws, size_t ws_size,
                              hipStream_t stream) {
    const float* edge_pred = (const float*)d_in[0];
    const int*   edge_index = (const int*)d_in[1];   // [2, E]: row0 = src, row1 = dst
    const int*   matched   = (const int*)d_in[2];

    const int e = in_sizes[0];
    const int n = in_sizes[2];

    const int* src = edge_index;
    const int* dst = edge_index + e;

    unsigned long long* best = (unsigned long long*)d_ws;

    float* out_matched = (float*)d_out;
    float* out_winpred = out_matched + n;
    float* found       = out_matched + 2 * n;

    // Zero the best-table and the found_match scalar (async, graph-capturable).
    hipMemsetAsync(best, 0, (size_t)n * sizeof(unsigned long long), stream);
    hipMemsetAsync(found, 0, sizeof(float), stream);

    const int block = 256;
    int grid_e = (e + block - 1) / block;
    if (grid_e > 8192) grid_e = 8192;
    edge_kernel<<<grid_e, block, 0, stream>>>(edge_pred, dst, best, e);

    int grid_n = (n + block - 1) / block;
    node_kernel<<<grid_n, block, 0, stream>>>(best, matched, src,
                                              out_matched, out_winpred, found, n);
}

// Round 2
// 328.816 us; speedup vs baseline: 1.5285x; 1.5285x over previous
//
#include <hip/hip_runtime.h>

// Segmented argmax (first-max tie-break) via packed u64 max.
// packed = (pred_bits << 32) | (0xFFFFFFFF - edge_idx); 0 = "no edge" sentinel.
//
// Round-1 fix: device-scope atomicMax generated 32B of HBM write traffic per
// edge (400 MB total, 10% BW, 490us). Now: 8 per-XCD replica tables selected
// by hardware XCC_ID; workgroup-scope atomics execute in the local XCD L2
// (no sc1 write-through), plus a read-filter so only improving candidates
// issue an RMW at all. A merge kernel folds the 8 replicas.

#define NXCD 8

__device__ __forceinline__ unsigned get_xcc_id() {
    unsigned x;
    asm volatile("s_getreg_b32 %0, hwreg(HW_REG_XCC_ID)" : "=s"(x));
    return x & (NXCD - 1);
}

__device__ __forceinline__ unsigned long long pack(float p, unsigned i) {
    return ((unsigned long long)__float_as_uint(p) << 32) |
           (unsigned long long)(0xFFFFFFFFu - i);
}

template <bool LOCAL>
__global__ void edge_kernel(const float* __restrict__ pred,
                            const int* __restrict__ dst,
                            unsigned long long* __restrict__ best,
                            int e, int n) {
    unsigned long long* tbl =
        LOCAL ? best + (size_t)get_xcc_id() * n : best;

    int tid = blockIdx.x * blockDim.x + threadIdx.x;
    int stride = gridDim.x * blockDim.x;

    // 4 edges per iteration via vector loads.
    int nvec = e >> 2;
    for (int v = tid; v < nvec; v += stride) {
        float4 p4 = ((const float4*)pred)[v];
        int4 d4 = ((const int4*)dst)[v];
        unsigned base = (unsigned)(v << 2);
        #pragma unroll
        for (int k = 0; k < 4; ++k) {
            float p = (k == 0) ? p4.x : (k == 1) ? p4.y : (k == 2) ? p4.z : p4.w;
            int d = (k == 0) ? d4.x : (k == 1) ? d4.y : (k == 2) ? d4.z : d4.w;
            unsigned long long packed = pack(p, base + k);
            if (tbl[d] < packed) {   // stale-read filter: value only grows
                if (LOCAL)
                    __hip_atomic_fetch_max(&tbl[d], packed, __ATOMIC_RELAXED,
                                           __HIP_MEMORY_SCOPE_WORKGROUP);
                else
                    __hip_atomic_fetch_max(&tbl[d], packed, __ATOMIC_RELAXED,
                                           __HIP_MEMORY_SCOPE_AGENT);
            }
        }
    }
    // tail
    for (int i = (nvec << 2) + tid; i < e; i += stride) {
        unsigned long long packed = pack(pred[i], (unsigned)i);
        int d = dst[i];
        if (tbl[d] < packed) {
            if (LOCAL)
                __hip_atomic_fetch_max(&tbl[d], packed, __ATOMIC_RELAXED,
                                       __HIP_MEMORY_SCOPE_WORKGROUP);
            else
                __hip_atomic_fetch_max(&tbl[d], packed, __ATOMIC_RELAXED,
                                       __HIP_MEMORY_SCOPE_AGENT);
        }
    }
}

__global__ void node_kernel(const unsigned long long* __restrict__ best,
                            const int* __restrict__ matched,
                            const int* __restrict__ src,
                            float* __restrict__ out_matched,
                            float* __restrict__ out_winpred,
                            float* __restrict__ found,
                            int n, int nrep) {
    int i = blockIdx.x * blockDim.x + threadIdx.x;
    if (i >= n) return;
    unsigned long long b = 0ULL;
    for (int r = 0; r < nrep; ++r) {
        unsigned long long v = best[(size_t)r * n + i];
        b = (v > b) ? v : b;
    }
    int m = matched[i];
    int nm = m;
    float wp = 0.0f;
    if (b != 0ULL) {
        wp = __uint_as_float((unsigned int)(b >> 32));
        unsigned int idx = 0xFFFFFFFFu - (unsigned int)(b & 0xFFFFFFFFu);
        if (m == -1 && wp > 0.5f) {
            nm = matched[src[idx]];
            *found = 1.0f;   // benign race: every writer stores 1.0f
        }
    }
    out_matched[i] = (float)nm;
    out_winpred[i] = wp;
}

extern "C" void kernel_launch(void* const* d_in, const int* in_sizes, int n_in,
                              void* d_out, int out_size, void* d_ws, size_t ws_size,
                              hipStream_t stream) {
    const float* edge_pred = (const float*)d_in[0];
    const int*   edge_index = (const int*)d_in[1];   // [2, E]: row0 = src, row1 = dst
    const int*   matched   = (const int*)d_in[2];

    const int e = in_sizes[0];
    const int n = in_sizes[2];

    const int* src = edge_index;
    const int* dst = edge_index + e;

    unsigned long long* best = (unsigned long long*)d_ws;

    float* out_matched = (float*)d_out;
    float* out_winpred = out_matched + n;
    float* found       = out_matched + 2 * n;

    const size_t need_local = (size_t)NXCD * n * sizeof(unsigned long long);
    const bool local = ws_size >= need_local;
    const int nrep = local ? NXCD : 1;

    hipMemsetAsync(best, 0, (size_t)nrep * n * sizeof(unsigned long long), stream);
    hipMemsetAsync(found, 0, sizeof(float), stream);

    const int block = 256;
    int grid_e = ((e >> 2) + block - 1) / block;
    if (grid_e > 8192) grid_e = 8192;
    if (grid_e < 1) grid_e = 1;
    if (local)
        edge_kernel<true><<<grid_e, block, 0, stream>>>(edge_pred, dst, best, e, n);
    else
        edge_kernel<false><<<grid_e, block, 0, stream>>>(edge_pred, dst, best, e, n);

    int grid_n = (n + block - 1) / block;
    node_kernel<<<grid_n, block, 0, stream>>>(best, matched, src,
                                              out_matched, out_winpred, found,
                                              n, nrep);
}